// Round 2
// baseline (8561.045 us; speedup 1.0000x reference)
//
#include <hip/hip_runtime.h>
#include <math.h>

#define T_LEN 24
#define NUU 2000
#define NLL 5000
#define NE 40000
#define CH 128
#define NH 4
#define HD 32
#define TCHUNK 8

static inline int cdiv(int a, int b) { return (a + b - 1) / b; }

// ---------------- CSR build ----------------
__global__ void fill_zero_int(int* __restrict__ p, int n) {
    int i = blockIdx.x * blockDim.x + threadIdx.x;
    if (i < n) p[i] = 0;
}

__global__ void histo_kernel(const int* __restrict__ dst, int* __restrict__ deg, int n) {
    int idx = blockIdx.x * blockDim.x + threadIdx.x;
    if (idx >= T_LEN * NE) return;
    int t = idx / NE;
    atomicAdd(&deg[t * n + dst[idx]], 1);
}

__global__ __launch_bounds__(256) void scan_off(const int* __restrict__ deg, int* __restrict__ offo, int n) {
    __shared__ int part[256];
    int t = blockIdx.x, tid = threadIdx.x;
    int items = (n + 255) / 256;
    int start = tid * items, end = min(start + items, n);
    const int* dt = deg + t * n;
    int s = 0;
    for (int i = start; i < end; ++i) s += dt[i];
    part[tid] = s;
    __syncthreads();
    for (int d = 1; d < 256; d <<= 1) {
        int v = (tid >= d) ? part[tid - d] : 0;
        __syncthreads();
        part[tid] += v;
        __syncthreads();
    }
    int run = part[tid] - s;  // exclusive prefix
    int* ot = offo + t * (n + 1);
    if (tid == 0) ot[0] = 0;
    for (int i = start; i < end; ++i) { run += dt[i]; ot[i + 1] = run; }
}

__global__ void copy_cur(const int* __restrict__ offo, int* __restrict__ cur, int n) {
    int idx = blockIdx.x * blockDim.x + threadIdx.x;
    if (idx >= T_LEN * n) return;
    int t = idx / n, i = idx - t * n;
    cur[idx] = offo[t * (n + 1) + i];
}

__global__ void scatter_perm(const int* __restrict__ dst, int* __restrict__ cur,
                             int* __restrict__ perm, int n) {
    int idx = blockIdx.x * blockDim.x + threadIdx.x;
    if (idx >= T_LEN * NE) return;
    int t = idx / NE, e = idx - t * NE;
    int d = dst[idx];
    int pos = atomicAdd(&cur[t * n + d], 1);
    perm[t * NE + pos] = e;
}

// ---------------- fused relation weights ----------------
__global__ __launch_bounds__(256) void build_fused(
    const float* __restrict__ w,   // [4,128,128] (layer base)
    const float* __restrict__ b,   // [4,128]
    const float* __restrict__ ra,  // [H,32,32]
    const float* __restrict__ rm,  // [H,32,32]
    float* __restrict__ Wf, float* __restrict__ bf) {
    int idx = blockIdx.x * 256 + threadIdx.x;
    if (idx >= 128 * 384) return;
    int c = idx / 384, col = idx - c * 384;
    if (col < 128) {
        Wf[c * 384 + col] = w[16384 + c * 128 + col];
        if (c == 0) bf[col] = b[128 + col];
    } else {
        int sec = (col - 128) >> 7;
        int hc = (col - 128) & 127;
        int h = hc >> 5, e2 = hc & 31;
        const float* A = (sec == 0 ? ra : rm) + h * 1024;
        const float* wsrc = w + (sec == 0 ? 0 : 2) * 16384;
        const float* bsrc = b + (sec == 0 ? 0 : 2) * 128;
        float s = 0.f, sb = 0.f;
#pragma unroll
        for (int d = 0; d < 32; ++d) {
            float a = A[d * 32 + e2];
            s += wsrc[c * 128 + h * 32 + d] * a;
            sb += bsrc[h * 32 + d] * a;
        }
        Wf[c * 384 + col] = s;
        if (c == 0) bf[col] = sb;
    }
}

__device__ __forceinline__ float gelu_f(float v) {
    return 0.5f * v * (1.f + erff(v * 0.70710678118654752f));
}

// ---------------- GEMM: C[M,NC] = epi( A[M,128] @ W[128,NC] + bias ) ----------------
// GATHER: A row index via ids. EPI: 0 none, 1 relu, 2 gelu(A) then skip-blend
template <bool GATHER, int EPI>
__global__ __launch_bounds__(256) void gemm_k128(
    const float* __restrict__ A, const int* __restrict__ ids,
    const float* __restrict__ W, const float* __restrict__ bias,
    float* __restrict__ C, const float* __restrict__ Xold,
    const float* __restrict__ skipPtr, int M, int NC) {
    __shared__ float As[32][68];
    __shared__ float Bs[32][68];
    const int tid = threadIdx.x;
    const int tx = tid & 15, ty = tid >> 4;
    const int m0 = blockIdx.x * 64, n0 = blockIdx.y * 64;

    const int lam = tid >> 2;        // 0..63 tile row
    const int lak = (tid & 3) * 8;   // k offset in chunk
    const int lbk = tid >> 3;        // 0..31
    const int lbn = (tid & 7) * 8;

    int arow = m0 + lam;
    if (GATHER) arow = ids[arow];
    const float* aptr = A + (size_t)arow * 128 + lak;
    const float* bptr = W + (size_t)lbk * NC + n0 + lbn;

    float acc[4][4];
#pragma unroll
    for (int i = 0; i < 4; i++)
#pragma unroll
        for (int j = 0; j < 4; j++) acc[i][j] = 0.f;

#pragma unroll
    for (int kt = 0; kt < 4; ++kt) {
        float4 av0 = *(const float4*)(aptr + kt * 32);
        float4 av1 = *(const float4*)(aptr + kt * 32 + 4);
        if (EPI == 2) {  // gelu on the aggregation input, fused
            av0.x = gelu_f(av0.x); av0.y = gelu_f(av0.y);
            av0.z = gelu_f(av0.z); av0.w = gelu_f(av0.w);
            av1.x = gelu_f(av1.x); av1.y = gelu_f(av1.y);
            av1.z = gelu_f(av1.z); av1.w = gelu_f(av1.w);
        }
        float4 bv0 = *(const float4*)(bptr + (size_t)(kt * 32) * NC);
        float4 bv1 = *(const float4*)(bptr + (size_t)(kt * 32) * NC + 4);
        __syncthreads();
        As[lak + 0][lam] = av0.x; As[lak + 1][lam] = av0.y;
        As[lak + 2][lam] = av0.z; As[lak + 3][lam] = av0.w;
        As[lak + 4][lam] = av1.x; As[lak + 5][lam] = av1.y;
        As[lak + 6][lam] = av1.z; As[lak + 7][lam] = av1.w;
        *(float4*)&Bs[lbk][lbn] = bv0;
        *(float4*)&Bs[lbk][lbn + 4] = bv1;
        __syncthreads();
#pragma unroll
        for (int kk = 0; kk < 32; ++kk) {
            float a4[4], b4[4];
            *(float4*)a4 = *(const float4*)&As[kk][ty * 4];
            *(float4*)b4 = *(const float4*)&Bs[kk][tx * 4];
#pragma unroll
            for (int i = 0; i < 4; i++)
#pragma unroll
                for (int j = 0; j < 4; j++) acc[i][j] = fmaf(a4[i], b4[j], acc[i][j]);
        }
    }

    float g = 0.f;
    if (EPI == 2) g = 1.f / (1.f + expf(-skipPtr[0]));
#pragma unroll
    for (int i = 0; i < 4; i++) {
        int r = m0 + ty * 4 + i;
        float vv[4];
#pragma unroll
        for (int j = 0; j < 4; j++) {
            int c = n0 + tx * 4 + j;
            float x = acc[i][j] + bias[c];
            if (EPI == 1) x = fmaxf(x, 0.f);
            vv[j] = x;
        }
        if (EPI == 2) {
            float xo4[4];
            *(float4*)xo4 = *(const float4*)(Xold + (size_t)r * NC + n0 + tx * 4);
#pragma unroll
            for (int j = 0; j < 4; j++) vv[j] = g * vv[j] + (1.f - g) * xo4[j];
        }
        *(float4*)(C + (size_t)r * NC + n0 + tx * 4) = *(float4*)vv;
    }
}

// ---------------- edge aggregation (online segment softmax, folded) ----------------
// 4 threads ("slots") per (t_local, dst_node, head); slot partials merged via shfl.
// lane layout: bits[1:0]=head, bits[3:2]=slot -> 4 consecutive lanes read one
// contiguous 128B k/m segment; butterfly combine over xor 4, 8.
__global__ __launch_bounds__(256) void agg_edges(
    const float* __restrict__ qkmD,  // [TCHUNK*nDst, 384] q at cols 0..127
    const float* __restrict__ qkmS,  // [TCHUNK*nSrc, 384] kr at 128.., mr at 256..
    const int* __restrict__ off,     // [T_LEN, nDst+1]
    const int* __restrict__ perm,    // [T_LEN, NE]
    const int* __restrict__ srcA,    // [T_LEN, NE]
    const float* __restrict__ relp,  // [H]
    float* __restrict__ agg,         // [TCHUNK*nDst, 128]
    int nDst, int nSrc, int tBase) {
    int idx = blockIdx.x * 256 + threadIdx.x;
    int total = TCHUNK * nDst * NH * 4;
    if (idx >= total) return;
    int h = idx & 3;
    int slot = (idx >> 2) & 3;
    int node = (idx >> 4) % nDst;
    int tl = (idx >> 4) / nDst;
    int t = tBase + tl;

    size_t drow = (size_t)(tl * nDst + node);
    float p = relp[h] * 0.17677669529663687f;  // rel_p/sqrt(32)

    const float4* qp = (const float4*)(qkmD + drow * 384 + h * HD);
    float4 qr[8];
#pragma unroll
    for (int j = 0; j < 8; j++) {
        float4 v = qp[j];
        v.x *= p; v.y *= p; v.z *= p; v.w *= p;
        qr[j] = v;
    }

    float m = -INFINITY, z = 0.f;
    float acc[HD];
#pragma unroll
    for (int d = 0; d < HD; d++) acc[d] = 0.f;

    int e0 = off[t * (nDst + 1) + node], e1 = off[t * (nDst + 1) + node + 1];
    const int* permT = perm + (size_t)t * NE;
    const int* srcT = srcA + (size_t)t * NE;

    for (int i = e0 + slot; i < e1; i += 4) {
        int e = permT[i];
        int s = srcT[e];
        const float4* kp = (const float4*)(qkmS + ((size_t)(tl * nSrc + s)) * 384 + 128 + h * HD);
        float4 kv[8], mv[8];
#pragma unroll
        for (int j = 0; j < 8; j++) kv[j] = kp[j];
#pragma unroll
        for (int j = 0; j < 8; j++) mv[j] = kp[j + 32];  // +128 floats
        float dot = 0.f;
#pragma unroll
        for (int j = 0; j < 8; j++) {
            dot = fmaf(qr[j].x, kv[j].x, dot);
            dot = fmaf(qr[j].y, kv[j].y, dot);
            dot = fmaf(qr[j].z, kv[j].z, dot);
            dot = fmaf(qr[j].w, kv[j].w, dot);
        }
        float mn = fmaxf(m, dot);          // first iter: m=-inf -> mn=dot (finite)
        float c = __expf(m - mn);          // -inf - finite -> 0, safe
        float w = __expf(dot - mn);
        z = z * c + w;
        const float* mf = (const float*)mv;
#pragma unroll
        for (int d = 0; d < HD; d++) acc[d] = fmaf(w, mf[d], acc[d] * c);
        m = mn;
    }

    // merge 4 slot partials: lanes differ in bits [3:2]
#pragma unroll
    for (int lm = 4; lm <= 8; lm <<= 1) {
        float mo = __shfl_xor(m, lm);
        float zo = __shfl_xor(z, lm);
        float mn = fmaxf(m, mo);
        float s1 = (m > -INFINITY) ? __expf(m - mn) : 0.f;
        float s2 = (mo > -INFINITY) ? __expf(mo - mn) : 0.f;
        z = z * s1 + zo * s2;
#pragma unroll
        for (int d = 0; d < HD; d++) {
            float ao = __shfl_xor(acc[d], lm);
            acc[d] = acc[d] * s1 + ao * s2;
        }
        m = mn;
    }

    if (slot == 0) {
        float inv = 1.f / (z + 1e-16f);
        float* op = agg + drow * CH + h * HD;
#pragma unroll
        for (int d = 0; d < HD; d++) op[d] = acc[d] * inv;
    }
}

__global__ void gather_traj(const float* __restrict__ tkg, const int* __restrict__ traj,
                            const int* __restrict__ tki, float* __restrict__ outp) {
    int idx = blockIdx.x * blockDim.x + threadIdx.x;
    if (idx >= 64 * 128 * 128) return;
    int r = idx >> 7, c2 = idx & 127;
    int t = tki[r], n = traj[r];
    outp[idx] = tkg[((size_t)t * NLL + n) * CH + c2];
}

// ---------------- launch ----------------
extern "C" void kernel_launch(void* const* d_in, const int* in_sizes, int n_in,
                              void* d_out, int out_size, void* d_ws, size_t ws_size,
                              hipStream_t stream) {
    (void)in_sizes; (void)n_in; (void)out_size; (void)ws_size;
    const float* user_emb = (const float*)d_in[0];
    const float* loc_emb = (const float*)d_in[1];
    const float* lin_user_w = (const float*)d_in[2];
    const float* lin_user_b = (const float*)d_in[3];
    const float* lin_loc_w = (const float*)d_in[4];
    const float* lin_loc_b = (const float*)d_in[5];
    const float* w_user = (const float*)d_in[6];
    const float* b_user = (const float*)d_in[7];
    const float* w_loc = (const float*)d_in[8];
    const float* b_loc = (const float*)d_in[9];
    const float* rel_a = (const float*)d_in[10];
    const float* rel_m = (const float*)d_in[11];
    const float* rel_p = (const float*)d_in[12];
    const float* skip = (const float*)d_in[13];
    const float* lin2_w = (const float*)d_in[14];
    const float* lin2_b = (const float*)d_in[15];
    const int* user_ids = (const int*)d_in[16];
    const int* loc_ids = (const int*)d_in[17];
    const int* ei_ul_src = (const int*)d_in[18];
    const int* ei_ul_dst = (const int*)d_in[19];
    const int* ei_lu_src = (const int*)d_in[20];
    const int* ei_lu_dst = (const int*)d_in[21];
    const int* traj = (const int*)d_in[22];
    const int* tkg_idx = (const int*)d_in[23];
    float* outp = (float*)d_out;

    size_t woff = 0;
    char* base = (char*)d_ws;
    auto carve = [&](size_t bytes) -> void* {
        void* p = base + woff;
        woff += (bytes + 255) & ~(size_t)255;
        return p;
    };
    float* xu = (float*)carve((size_t)T_LEN * NUU * 128 * 4);
    float* xl = (float*)carve((size_t)T_LEN * NLL * 128 * 4);
    float* qkm_u = (float*)carve((size_t)TCHUNK * NUU * 384 * 4);
    float* qkm_l = (float*)carve((size_t)TCHUNK * NLL * 384 * 4);
    float* agg_u = (float*)carve((size_t)TCHUNK * NUU * 128 * 4);
    float* agg_l = (float*)carve((size_t)TCHUNK * NLL * 128 * 4);
    float* wf_u = (float*)carve(128 * 384 * 4);
    float* bf_u = (float*)carve(384 * 4);
    float* wf_l = (float*)carve(128 * 384 * 4);
    float* bf_l = (float*)carve(384 * 4);
    int* deg_ul = (int*)carve((size_t)T_LEN * NLL * 4);
    int* cur_ul = (int*)carve((size_t)T_LEN * NLL * 4);
    int* off_ul = (int*)carve((size_t)T_LEN * (NLL + 1) * 4);
    int* perm_ul = (int*)carve((size_t)T_LEN * NE * 4);
    int* deg_lu = (int*)carve((size_t)T_LEN * NUU * 4);
    int* cur_lu = (int*)carve((size_t)T_LEN * NUU * 4);
    int* off_lu = (int*)carve((size_t)T_LEN * (NUU + 1) * 4);
    int* perm_lu = (int*)carve((size_t)T_LEN * NE * 4);

    // ---- CSR build ----
    fill_zero_int<<<cdiv(T_LEN * NLL, 256), 256, 0, stream>>>(deg_ul, T_LEN * NLL);
    fill_zero_int<<<cdiv(T_LEN * NUU, 256), 256, 0, stream>>>(deg_lu, T_LEN * NUU);
    histo_kernel<<<cdiv(T_LEN * NE, 256), 256, 0, stream>>>(ei_ul_dst, deg_ul, NLL);
    histo_kernel<<<cdiv(T_LEN * NE, 256), 256, 0, stream>>>(ei_lu_dst, deg_lu, NUU);
    scan_off<<<T_LEN, 256, 0, stream>>>(deg_ul, off_ul, NLL);
    scan_off<<<T_LEN, 256, 0, stream>>>(deg_lu, off_lu, NUU);
    copy_cur<<<cdiv(T_LEN * NLL, 256), 256, 0, stream>>>(off_ul, cur_ul, NLL);
    copy_cur<<<cdiv(T_LEN * NUU, 256), 256, 0, stream>>>(off_lu, cur_lu, NUU);
    scatter_perm<<<cdiv(T_LEN * NE, 256), 256, 0, stream>>>(ei_ul_dst, cur_ul, perm_ul, NLL);
    scatter_perm<<<cdiv(T_LEN * NE, 256), 256, 0, stream>>>(ei_lu_dst, cur_lu, perm_lu, NUU);

    // ---- embed + linear + relu ----
    gemm_k128<true, 1><<<dim3(T_LEN * NUU / 64, 2), 256, 0, stream>>>(
        user_emb, user_ids, lin_user_w, lin_user_b, xu, nullptr, nullptr, T_LEN * NUU, 128);
    gemm_k128<true, 1><<<dim3(T_LEN * NLL / 64, 2), 256, 0, stream>>>(
        loc_emb, loc_ids, lin_loc_w, lin_loc_b, xl, nullptr, nullptr, T_LEN * NLL, 128);

    // ---- HGT layers ----
    for (int l = 0; l < 2; ++l) {
        build_fused<<<cdiv(128 * 384, 256), 256, 0, stream>>>(
            w_user + (size_t)l * 4 * 16384, b_user + l * 512,
            rel_a + (size_t)(l * 2 + 0) * 4096, rel_m + (size_t)(l * 2 + 0) * 4096, wf_u, bf_u);
        build_fused<<<cdiv(128 * 384, 256), 256, 0, stream>>>(
            w_loc + (size_t)l * 4 * 16384, b_loc + l * 512,
            rel_a + (size_t)(l * 2 + 1) * 4096, rel_m + (size_t)(l * 2 + 1) * 4096, wf_l, bf_l);

        for (int tb = 0; tb < T_LEN; tb += TCHUNK) {
            const int MU = TCHUNK * NUU;   // 16000
            const int ML = TCHUNK * NLL;   // 40000
            float* xu_c = xu + (size_t)tb * NUU * 128;
            float* xl_c = xl + (size_t)tb * NLL * 128;

            gemm_k128<false, 0><<<dim3(MU / 64, 6), 256, 0, stream>>>(
                xu_c, nullptr, wf_u, bf_u, qkm_u, nullptr, nullptr, MU, 384);
            gemm_k128<false, 0><<<dim3(ML / 64, 6), 256, 0, stream>>>(
                xl_c, nullptr, wf_l, bf_l, qkm_l, nullptr, nullptr, ML, 384);

            agg_edges<<<cdiv(TCHUNK * NLL * NH * 4, 256), 256, 0, stream>>>(
                qkm_l, qkm_u, off_ul, perm_ul, ei_ul_src, rel_p + (l * 2 + 0) * 4,
                agg_l, NLL, NUU, tb);
            agg_edges<<<cdiv(TCHUNK * NUU * NH * 4, 256), 256, 0, stream>>>(
                qkm_u, qkm_l, off_lu, perm_lu, ei_lu_src, rel_p + (l * 2 + 1) * 4,
                agg_u, NUU, NLL, tb);

            gemm_k128<false, 2><<<dim3(MU / 64, 2), 256, 0, stream>>>(
                agg_u, nullptr, w_user + (size_t)(l * 4 + 3) * 16384, b_user + l * 512 + 384,
                xu_c, xu_c, skip + l * 2 + 0, MU, 128);
            gemm_k128<false, 2><<<dim3(ML / 64, 2), 256, 0, stream>>>(
                agg_l, nullptr, w_loc + (size_t)(l * 4 + 3) * 16384, b_loc + l * 512 + 384,
                xl_c, xl_c, skip + l * 2 + 1, ML, 128);
        }
    }

    // ---- lin2 -> tkg_out region of d_out ----
    float* tkg_out = outp + (size_t)64 * 128 * 128;
    gemm_k128<false, 0><<<dim3(T_LEN * NLL / 64, 2), 256, 0, stream>>>(
        xl, nullptr, lin2_w, lin2_b, tkg_out, nullptr, nullptr, T_LEN * NLL, 128);

    // ---- trajectory gather -> first region of d_out ----
    gather_traj<<<cdiv(64 * 128 * 128, 256), 256, 0, stream>>>(tkg_out, traj, tkg_idx, outp);
}

// Round 3
// 2280.623 us; speedup vs baseline: 3.7538x; 3.7538x over previous
//
#include <hip/hip_runtime.h>
#include <math.h>

#define T_LEN 24
#define NUU 2000
#define NLL 5000
#define NE 40000
#define CH 128
#define NH 4
#define HD 32
#define TCHUNK 8

typedef __attribute__((ext_vector_type(8))) short short8;
typedef __attribute__((ext_vector_type(4))) float f32x4;

static inline int cdiv(int a, int b) { return (a + b - 1) / b; }

__device__ __forceinline__ unsigned short f2bf(float x) {
    unsigned u = __float_as_uint(x);
    unsigned r = (u + 0x7fff + ((u >> 16) & 1)) >> 16;  // RNE
    return (unsigned short)r;
}
__device__ __forceinline__ float bf2f(unsigned short h) {
    return __uint_as_float(((unsigned)h) << 16);
}

// ---------------- CSR build ----------------
__global__ void fill_zero_int(int* __restrict__ p, int n) {
    int i = blockIdx.x * blockDim.x + threadIdx.x;
    if (i < n) p[i] = 0;
}

__global__ void histo_kernel(const int* __restrict__ dst, int* __restrict__ deg, int n) {
    int idx = blockIdx.x * blockDim.x + threadIdx.x;
    if (idx >= T_LEN * NE) return;
    int t = idx / NE;
    atomicAdd(&deg[t * n + dst[idx]], 1);
}

__global__ __launch_bounds__(256) void scan_off(const int* __restrict__ deg, int* __restrict__ offo, int n) {
    __shared__ int part[256];
    int t = blockIdx.x, tid = threadIdx.x;
    int items = (n + 255) / 256;
    int start = tid * items, end = min(start + items, n);
    const int* dt = deg + t * n;
    int s = 0;
    for (int i = start; i < end; ++i) s += dt[i];
    part[tid] = s;
    __syncthreads();
    for (int d = 1; d < 256; d <<= 1) {
        int v = (tid >= d) ? part[tid - d] : 0;
        __syncthreads();
        part[tid] += v;
        __syncthreads();
    }
    int run = part[tid] - s;
    int* ot = offo + t * (n + 1);
    if (tid == 0) ot[0] = 0;
    for (int i = start; i < end; ++i) { run += dt[i]; ot[i + 1] = run; }
}

__global__ void copy_cur(const int* __restrict__ offo, int* __restrict__ cur, int n) {
    int idx = blockIdx.x * blockDim.x + threadIdx.x;
    if (idx >= T_LEN * n) return;
    int t = idx / n, i = idx - t * n;
    cur[idx] = offo[t * (n + 1) + i];
}

__global__ void scatter_perm(const int* __restrict__ dst, int* __restrict__ cur,
                             int* __restrict__ perm, int n) {
    int idx = blockIdx.x * blockDim.x + threadIdx.x;
    if (idx >= T_LEN * NE) return;
    int t = idx / NE, e = idx - t * NE;
    int d = dst[idx];
    int pos = atomicAdd(&cur[t * n + d], 1);
    perm[t * NE + pos] = e;
}

// ---------------- fused relation weights (f32) ----------------
__global__ __launch_bounds__(256) void build_fused(
    const float* __restrict__ w, const float* __restrict__ b,
    const float* __restrict__ ra, const float* __restrict__ rm,
    float* __restrict__ Wf, float* __restrict__ bf) {
    int idx = blockIdx.x * 256 + threadIdx.x;
    if (idx >= 128 * 384) return;
    int c = idx / 384, col = idx - c * 384;
    if (col < 128) {
        Wf[c * 384 + col] = w[16384 + c * 128 + col];
        if (c == 0) bf[col] = b[128 + col];
    } else {
        int sec = (col - 128) >> 7;
        int hc = (col - 128) & 127;
        int h = hc >> 5, e2 = hc & 31;
        const float* A = (sec == 0 ? ra : rm) + h * 1024;
        const float* wsrc = w + (sec == 0 ? 0 : 2) * 16384;
        const float* bsrc = b + (sec == 0 ? 0 : 2) * 128;
        float s = 0.f, sb = 0.f;
#pragma unroll
        for (int d = 0; d < 32; ++d) {
            float a = A[d * 32 + e2];
            s += wsrc[c * 128 + h * 32 + d] * a;
            sb += bsrc[h * 32 + d] * a;
        }
        Wf[c * 384 + col] = s;
        if (c == 0) bf[col] = sb;
    }
}

// ---------------- B prep: split f32 W[128][N] into fragment-ready bf16 hi/lo ----------------
// layout (ushort units): ntile*16384 + hilo*8192 + n_local*128 + k
__global__ void bprep_kernel(const float* __restrict__ W, unsigned short* __restrict__ prep, int N) {
    int idx = blockIdx.x * blockDim.x + threadIdx.x;
    if (idx >= 128 * N) return;
    int k = idx / N, n = idx - k * N;
    float v = W[idx];
    unsigned short hi = f2bf(v);
    unsigned short lo = f2bf(v - bf2f(hi));
    int nt = n >> 6, nl = n & 63;
    size_t base = (size_t)nt * 16384 + (size_t)nl * 128 + k;
    prep[base] = hi;
    prep[base + 8192] = lo;
}

// ---------------- MFMA GEMM: C[M,N] = epi( A[M,128] @ W[128,N] + bias ) ----------------
// split-bf16 3-term: Ah*Bh + Ah*Bl + Al*Bh.  BM=128, BN=64, 4 waves (2x2).
// GATHER: A row via ids. EPI: 0 none, 1 relu, 2 skip-blend
template <bool GATHER, int EPI>
__global__ __launch_bounds__(256) void gemm_mfma(
    const float* __restrict__ A, const int* __restrict__ ids,
    const unsigned short* __restrict__ prep, const float* __restrict__ bias,
    float* __restrict__ C, const float* __restrict__ Xold,
    const float* __restrict__ skipPtr, int M, int NC) {
    __shared__ __align__(16) char smem[65536];  // Ah [128][256B] + Al at +32768, XOR-swizzled

    const int tid = threadIdx.x;
    const int lane = tid & 63;
    const int wid = tid >> 6;
    const int wm = wid >> 1, wn = wid & 1;
    const int m0 = blockIdx.x * 128;
    const int n0 = blockIdx.y * 64;
    const int l15 = lane & 15, l4 = lane >> 4;

    // ---- B fragments straight from prep (L2-hot) ----
    const unsigned short* bp = prep + (size_t)blockIdx.y * 16384;
    short8 bh[2][4], bl[2][4];  // [nf][ks]
#pragma unroll
    for (int nf = 0; nf < 2; ++nf) {
        int ncol = wn * 32 + nf * 16 + l15;
#pragma unroll
        for (int ks = 0; ks < 4; ++ks) {
            size_t off = (size_t)ncol * 128 + ks * 32 + l4 * 8;
            bh[nf][ks] = *(const short8*)(bp + off);
            bl[nf][ks] = *(const short8*)(bp + 8192 + off);
        }
    }

    // ---- stage A tile (f32 -> bf16 hi/lo, swizzled) ----
#pragma unroll
    for (int i = 0; i < 16; ++i) {
        int flat = i * 256 + tid;
        int r = flat >> 5, c4 = flat & 31;
        int gr = m0 + r;
        if (gr >= M) gr = M - 1;
        int arow = GATHER ? ids[gr] : gr;
        float4 v = *(const float4*)(A + (size_t)arow * 128 + c4 * 4);
        unsigned short h0 = f2bf(v.x), h1 = f2bf(v.y), h2 = f2bf(v.z), h3 = f2bf(v.w);
        unsigned short q0 = f2bf(v.x - bf2f(h0)), q1 = f2bf(v.y - bf2f(h1));
        unsigned short q2 = f2bf(v.z - bf2f(h2)), q3 = f2bf(v.w - bf2f(h3));
        uint2 hp, lp;
        hp.x = (unsigned)h0 | ((unsigned)h1 << 16);
        hp.y = (unsigned)h2 | ((unsigned)h3 << 16);
        lp.x = (unsigned)q0 | ((unsigned)q1 << 16);
        lp.y = (unsigned)q2 | ((unsigned)q3 << 16);
        int off = r * 256 + ((c4 * 8) ^ ((r & 7) << 4));
        *(uint2*)(smem + off) = hp;
        *(uint2*)(smem + 32768 + off) = lp;
    }
    __syncthreads();

    // ---- MFMA main loop ----
    f32x4 acc[4][2];
#pragma unroll
    for (int m = 0; m < 4; ++m)
#pragma unroll
        for (int nf = 0; nf < 2; ++nf) acc[m][nf] = (f32x4)0.f;

#pragma unroll
    for (int ks = 0; ks < 4; ++ks) {
        short8 ah[4], al[4];
#pragma unroll
        for (int m = 0; m < 4; ++m) {
            int row = wm * 64 + m * 16 + l15;
            int off = row * 256 + ((ks * 64 + l4 * 16) ^ ((row & 7) << 4));
            ah[m] = *(const short8*)(smem + off);
            al[m] = *(const short8*)(smem + 32768 + off);
        }
#pragma unroll
        for (int m = 0; m < 4; ++m)
#pragma unroll
            for (int nf = 0; nf < 2; ++nf) {
                acc[m][nf] = __builtin_amdgcn_mfma_f32_16x16x32_bf16(al[m], bh[nf][ks], acc[m][nf], 0, 0, 0);
                acc[m][nf] = __builtin_amdgcn_mfma_f32_16x16x32_bf16(ah[m], bl[nf][ks], acc[m][nf], 0, 0, 0);
                acc[m][nf] = __builtin_amdgcn_mfma_f32_16x16x32_bf16(ah[m], bh[nf][ks], acc[m][nf], 0, 0, 0);
            }
    }

    // ---- epilogue ----
    float g = 0.f;
    if (EPI == 2) g = 1.f / (1.f + expf(-skipPtr[0]));
    float bias_v[2];
#pragma unroll
    for (int nf = 0; nf < 2; ++nf) bias_v[nf] = bias[n0 + wn * 32 + nf * 16 + l15];

#pragma unroll
    for (int m = 0; m < 4; ++m) {
#pragma unroll
        for (int nf = 0; nf < 2; ++nf) {
            int gc = n0 + wn * 32 + nf * 16 + l15;
#pragma unroll
            for (int i = 0; i < 4; ++i) {
                int gr = m0 + wm * 64 + m * 16 + l4 * 4 + i;
                if (gr >= M) continue;
                float x = acc[m][nf][i] + bias_v[nf];
                if (EPI == 1) x = fmaxf(x, 0.f);
                if (EPI == 2) {
                    float xo = Xold[(size_t)gr * NC + gc];
                    x = g * x + (1.f - g) * xo;
                }
                C[(size_t)gr * NC + gc] = x;
            }
        }
    }
}

// ---------------- edge aggregation (R2 version, proven) ----------------
__global__ __launch_bounds__(256) void agg_edges(
    const float* __restrict__ qkmD, const float* __restrict__ qkmS,
    const int* __restrict__ off, const int* __restrict__ perm,
    const int* __restrict__ srcA, const float* __restrict__ relp,
    float* __restrict__ agg, int nDst, int nSrc, int tBase) {
    int idx = blockIdx.x * 256 + threadIdx.x;
    int total = TCHUNK * nDst * NH * 4;
    if (idx >= total) return;
    int h = idx & 3;
    int slot = (idx >> 2) & 3;
    int node = (idx >> 4) % nDst;
    int tl = (idx >> 4) / nDst;
    int t = tBase + tl;

    size_t drow = (size_t)(tl * nDst + node);
    float p = relp[h] * 0.17677669529663687f;

    const float4* qp = (const float4*)(qkmD + drow * 384 + h * HD);
    float4 qr[8];
#pragma unroll
    for (int j = 0; j < 8; j++) {
        float4 v = qp[j];
        v.x *= p; v.y *= p; v.z *= p; v.w *= p;
        qr[j] = v;
    }

    float m = -INFINITY, z = 0.f;
    float acc[HD];
#pragma unroll
    for (int d = 0; d < HD; d++) acc[d] = 0.f;

    int e0 = off[t * (nDst + 1) + node], e1 = off[t * (nDst + 1) + node + 1];
    const int* permT = perm + (size_t)t * NE;
    const int* srcT = srcA + (size_t)t * NE;

    for (int i = e0 + slot; i < e1; i += 4) {
        int e = permT[i];
        int s = srcT[e];
        const float4* kp = (const float4*)(qkmS + ((size_t)(tl * nSrc + s)) * 384 + 128 + h * HD);
        float4 kv[8], mv[8];
#pragma unroll
        for (int j = 0; j < 8; j++) kv[j] = kp[j];
#pragma unroll
        for (int j = 0; j < 8; j++) mv[j] = kp[j + 32];
        float dot = 0.f;
#pragma unroll
        for (int j = 0; j < 8; j++) {
            dot = fmaf(qr[j].x, kv[j].x, dot);
            dot = fmaf(qr[j].y, kv[j].y, dot);
            dot = fmaf(qr[j].z, kv[j].z, dot);
            dot = fmaf(qr[j].w, kv[j].w, dot);
        }
        float mn = fmaxf(m, dot);
        float c = __expf(m - mn);
        float w = __expf(dot - mn);
        z = z * c + w;
        const float* mf = (const float*)mv;
#pragma unroll
        for (int d = 0; d < HD; d++) acc[d] = fmaf(w, mf[d], acc[d] * c);
        m = mn;
    }

#pragma unroll
    for (int lm = 4; lm <= 8; lm <<= 1) {
        float mo = __shfl_xor(m, lm);
        float zo = __shfl_xor(z, lm);
        float mn = fmaxf(m, mo);
        float s1 = (m > -INFINITY) ? __expf(m - mn) : 0.f;
        float s2 = (mo > -INFINITY) ? __expf(mo - mn) : 0.f;
        z = z * s1 + zo * s2;
#pragma unroll
        for (int d = 0; d < HD; d++) {
            float ao = __shfl_xor(acc[d], lm);
            acc[d] = acc[d] * s1 + ao * s2;
        }
        m = mn;
    }

    if (slot == 0) {
        float inv = 1.f / (z + 1e-16f);
        float* op = agg + drow * CH + h * HD;
#pragma unroll
        for (int d = 0; d < HD; d++) op[d] = acc[d] * inv;
    }
}

__global__ void gelu_ip(float* __restrict__ x, int n) {
    int idx = blockIdx.x * blockDim.x + threadIdx.x;
    if (idx >= n) return;
    float v = x[idx];
    x[idx] = 0.5f * v * (1.f + erff(v * 0.70710678118654752f));
}

__global__ void gather_traj(const float* __restrict__ tkg, const int* __restrict__ traj,
                            const int* __restrict__ tki, float* __restrict__ outp) {
    int idx = blockIdx.x * blockDim.x + threadIdx.x;
    if (idx >= 64 * 128 * 128) return;
    int r = idx >> 7, c2 = idx & 127;
    int t = tki[r], n = traj[r];
    outp[idx] = tkg[((size_t)t * NLL + n) * CH + c2];
}

// ---------------- launch ----------------
extern "C" void kernel_launch(void* const* d_in, const int* in_sizes, int n_in,
                              void* d_out, int out_size, void* d_ws, size_t ws_size,
                              hipStream_t stream) {
    (void)in_sizes; (void)n_in; (void)out_size; (void)ws_size;
    const float* user_emb = (const float*)d_in[0];
    const float* loc_emb = (const float*)d_in[1];
    const float* lin_user_w = (const float*)d_in[2];
    const float* lin_user_b = (const float*)d_in[3];
    const float* lin_loc_w = (const float*)d_in[4];
    const float* lin_loc_b = (const float*)d_in[5];
    const float* w_user = (const float*)d_in[6];
    const float* b_user = (const float*)d_in[7];
    const float* w_loc = (const float*)d_in[8];
    const float* b_loc = (const float*)d_in[9];
    const float* rel_a = (const float*)d_in[10];
    const float* rel_m = (const float*)d_in[11];
    const float* rel_p = (const float*)d_in[12];
    const float* skip = (const float*)d_in[13];
    const float* lin2_w = (const float*)d_in[14];
    const float* lin2_b = (const float*)d_in[15];
    const int* user_ids = (const int*)d_in[16];
    const int* loc_ids = (const int*)d_in[17];
    const int* ei_ul_src = (const int*)d_in[18];
    const int* ei_ul_dst = (const int*)d_in[19];
    const int* ei_lu_src = (const int*)d_in[20];
    const int* ei_lu_dst = (const int*)d_in[21];
    const int* traj = (const int*)d_in[22];
    const int* tkg_idx = (const int*)d_in[23];
    float* outp = (float*)d_out;

    size_t woff = 0;
    char* base = (char*)d_ws;
    auto carve = [&](size_t bytes) -> void* {
        void* p = base + woff;
        woff += (bytes + 255) & ~(size_t)255;
        return p;
    };
    float* xu = (float*)carve((size_t)T_LEN * NUU * 128 * 4);
    float* xl = (float*)carve((size_t)T_LEN * NLL * 128 * 4);
    float* qkm_u = (float*)carve((size_t)TCHUNK * NUU * 384 * 4);
    float* qkm_l = (float*)carve((size_t)TCHUNK * NLL * 384 * 4);
    float* agg_u = (float*)carve((size_t)TCHUNK * NUU * 128 * 4);
    float* agg_l = (float*)carve((size_t)TCHUNK * NLL * 128 * 4);
    float* wf_u = (float*)carve(128 * 384 * 4);
    float* bf_u = (float*)carve(384 * 4);
    float* wf_l = (float*)carve(128 * 384 * 4);
    float* bf_l = (float*)carve(384 * 4);
    int* deg_ul = (int*)carve((size_t)T_LEN * NLL * 4);
    int* cur_ul = (int*)carve((size_t)T_LEN * NLL * 4);
    int* off_ul = (int*)carve((size_t)T_LEN * (NLL + 1) * 4);
    int* perm_ul = (int*)carve((size_t)T_LEN * NE * 4);
    int* deg_lu = (int*)carve((size_t)T_LEN * NUU * 4);
    int* cur_lu = (int*)carve((size_t)T_LEN * NUU * 4);
    int* off_lu = (int*)carve((size_t)T_LEN * (NUU + 1) * 4);
    int* perm_lu = (int*)carve((size_t)T_LEN * NE * 4);
    // bf16 hi/lo fragment-ready weight preps
    unsigned short* bp_lin_u = (unsigned short*)carve(128 * 512);
    unsigned short* bp_lin_l = (unsigned short*)carve(128 * 512);
    unsigned short* bp_lin2 = (unsigned short*)carve(128 * 512);
    unsigned short* bp_upd_u[2] = {(unsigned short*)carve(128 * 512), (unsigned short*)carve(128 * 512)};
    unsigned short* bp_upd_l[2] = {(unsigned short*)carve(128 * 512), (unsigned short*)carve(128 * 512)};
    unsigned short* bp_wf_u = (unsigned short*)carve(384 * 512);
    unsigned short* bp_wf_l = (unsigned short*)carve(384 * 512);

    // ---- CSR build ----
    fill_zero_int<<<cdiv(T_LEN * NLL, 256), 256, 0, stream>>>(deg_ul, T_LEN * NLL);
    fill_zero_int<<<cdiv(T_LEN * NUU, 256), 256, 0, stream>>>(deg_lu, T_LEN * NUU);
    histo_kernel<<<cdiv(T_LEN * NE, 256), 256, 0, stream>>>(ei_ul_dst, deg_ul, NLL);
    histo_kernel<<<cdiv(T_LEN * NE, 256), 256, 0, stream>>>(ei_lu_dst, deg_lu, NUU);
    scan_off<<<T_LEN, 256, 0, stream>>>(deg_ul, off_ul, NLL);
    scan_off<<<T_LEN, 256, 0, stream>>>(deg_lu, off_lu, NUU);
    copy_cur<<<cdiv(T_LEN * NLL, 256), 256, 0, stream>>>(off_ul, cur_ul, NLL);
    copy_cur<<<cdiv(T_LEN * NUU, 256), 256, 0, stream>>>(off_lu, cur_lu, NUU);
    scatter_perm<<<cdiv(T_LEN * NE, 256), 256, 0, stream>>>(ei_ul_dst, cur_ul, perm_ul, NLL);
    scatter_perm<<<cdiv(T_LEN * NE, 256), 256, 0, stream>>>(ei_lu_dst, cur_lu, perm_lu, NUU);

    // ---- weight preps (static ones) ----
    bprep_kernel<<<64, 256, 0, stream>>>(lin_user_w, bp_lin_u, 128);
    bprep_kernel<<<64, 256, 0, stream>>>(lin_loc_w, bp_lin_l, 128);
    bprep_kernel<<<64, 256, 0, stream>>>(lin2_w, bp_lin2, 128);
    for (int l = 0; l < 2; ++l) {
        bprep_kernel<<<64, 256, 0, stream>>>(w_user + (size_t)(l * 4 + 3) * 16384, bp_upd_u[l], 128);
        bprep_kernel<<<64, 256, 0, stream>>>(w_loc + (size_t)(l * 4 + 3) * 16384, bp_upd_l[l], 128);
    }

    // ---- embed + linear + relu ----
    gemm_mfma<true, 1><<<dim3(cdiv(T_LEN * NUU, 128), 2), 256, 0, stream>>>(
        user_emb, user_ids, bp_lin_u, lin_user_b, xu, nullptr, nullptr, T_LEN * NUU, 128);
    gemm_mfma<true, 1><<<dim3(cdiv(T_LEN * NLL, 128), 2), 256, 0, stream>>>(
        loc_emb, loc_ids, bp_lin_l, lin_loc_b, xl, nullptr, nullptr, T_LEN * NLL, 128);

    // ---- HGT layers ----
    for (int l = 0; l < 2; ++l) {
        build_fused<<<cdiv(128 * 384, 256), 256, 0, stream>>>(
            w_user + (size_t)l * 4 * 16384, b_user + l * 512,
            rel_a + (size_t)(l * 2 + 0) * 4096, rel_m + (size_t)(l * 2 + 0) * 4096, wf_u, bf_u);
        build_fused<<<cdiv(128 * 384, 256), 256, 0, stream>>>(
            w_loc + (size_t)l * 4 * 16384, b_loc + l * 512,
            rel_a + (size_t)(l * 2 + 1) * 4096, rel_m + (size_t)(l * 2 + 1) * 4096, wf_l, bf_l);
        bprep_kernel<<<192, 256, 0, stream>>>(wf_u, bp_wf_u, 384);
        bprep_kernel<<<192, 256, 0, stream>>>(wf_l, bp_wf_l, 384);

        for (int tb = 0; tb < T_LEN; tb += TCHUNK) {
            const int MU = TCHUNK * NUU;   // 16000
            const int ML = TCHUNK * NLL;   // 40000
            float* xu_c = xu + (size_t)tb * NUU * 128;
            float* xl_c = xl + (size_t)tb * NLL * 128;

            gemm_mfma<false, 0><<<dim3(cdiv(MU, 128), 6), 256, 0, stream>>>(
                xu_c, nullptr, bp_wf_u, bf_u, qkm_u, nullptr, nullptr, MU, 384);
            gemm_mfma<false, 0><<<dim3(cdiv(ML, 128), 6), 256, 0, stream>>>(
                xl_c, nullptr, bp_wf_l, bf_l, qkm_l, nullptr, nullptr, ML, 384);

            agg_edges<<<cdiv(TCHUNK * NLL * NH * 4, 256), 256, 0, stream>>>(
                qkm_l, qkm_u, off_ul, perm_ul, ei_ul_src, rel_p + (l * 2 + 0) * 4,
                agg_l, NLL, NUU, tb);
            agg_edges<<<cdiv(TCHUNK * NUU * NH * 4, 256), 256, 0, stream>>>(
                qkm_u, qkm_l, off_lu, perm_lu, ei_lu_src, rel_p + (l * 2 + 1) * 4,
                agg_u, NUU, NLL, tb);

            gelu_ip<<<cdiv(MU * 128, 256), 256, 0, stream>>>(agg_u, MU * 128);
            gelu_ip<<<cdiv(ML * 128, 256), 256, 0, stream>>>(agg_l, ML * 128);

            gemm_mfma<false, 2><<<dim3(cdiv(MU, 128), 2), 256, 0, stream>>>(
                agg_u, nullptr, bp_upd_u[l], b_user + l * 512 + 384,
                xu_c, xu_c, skip + l * 2 + 0, MU, 128);
            gemm_mfma<false, 2><<<dim3(cdiv(ML, 128), 2), 256, 0, stream>>>(
                agg_l, nullptr, bp_upd_l[l], b_loc + l * 512 + 384,
                xl_c, xl_c, skip + l * 2 + 1, ML, 128);
        }
    }

    // ---- lin2 -> tkg_out region of d_out ----
    float* tkg_out = outp + (size_t)64 * 128 * 128;
    gemm_mfma<false, 0><<<dim3(cdiv(T_LEN * NLL, 128), 2), 256, 0, stream>>>(
        xl, nullptr, bp_lin2, lin2_b, tkg_out, nullptr, nullptr, T_LEN * NLL, 128);

    // ---- trajectory gather ----
    gather_traj<<<cdiv(64 * 128 * 128, 256), 256, 0, stream>>>(tkg_out, traj, tkg_idx, outp);
}

// Round 4
// 1636.184 us; speedup vs baseline: 5.2323x; 1.3939x over previous
//
#include <hip/hip_runtime.h>
#include <math.h>

#define T_LEN 24
#define NUU 2000
#define NLL 5000
#define NE 40000
#define CH 128
#define NH 4
#define HD 32
#define TCHUNK 8

typedef __attribute__((ext_vector_type(8))) short short8;
typedef __attribute__((ext_vector_type(4))) float f32x4;

static inline int cdiv(int a, int b) { return (a + b - 1) / b; }

__device__ __forceinline__ unsigned short f2bf(float x) {
    unsigned u = __float_as_uint(x);
    unsigned r = (u + 0x7fff + ((u >> 16) & 1)) >> 16;  // RNE
    return (unsigned short)r;
}
__device__ __forceinline__ float bf2f(unsigned short h) {
    return __uint_as_float(((unsigned)h) << 16);
}
__device__ __forceinline__ float2 bf2x(unsigned u) {
    float2 r;
    r.x = __uint_as_float(u << 16);
    r.y = __uint_as_float(u & 0xffff0000u);
    return r;
}

// ---------------- CSR build ----------------
__global__ void fill_zero_int(int* __restrict__ p, int n) {
    int i = blockIdx.x * blockDim.x + threadIdx.x;
    if (i < n) p[i] = 0;
}

__global__ void histo_kernel(const int* __restrict__ dst, int* __restrict__ deg, int n) {
    int idx = blockIdx.x * blockDim.x + threadIdx.x;
    if (idx >= T_LEN * NE) return;
    int t = idx / NE;
    atomicAdd(&deg[t * n + dst[idx]], 1);
}

__global__ __launch_bounds__(256) void scan_off(const int* __restrict__ deg, int* __restrict__ offo, int n) {
    __shared__ int part[256];
    int t = blockIdx.x, tid = threadIdx.x;
    int items = (n + 255) / 256;
    int start = tid * items, end = min(start + items, n);
    const int* dt = deg + t * n;
    int s = 0;
    for (int i = start; i < end; ++i) s += dt[i];
    part[tid] = s;
    __syncthreads();
    for (int d = 1; d < 256; d <<= 1) {
        int v = (tid >= d) ? part[tid - d] : 0;
        __syncthreads();
        part[tid] += v;
        __syncthreads();
    }
    int run = part[tid] - s;
    int* ot = offo + t * (n + 1);
    if (tid == 0) ot[0] = 0;
    for (int i = start; i < end; ++i) { run += dt[i]; ot[i + 1] = run; }
}

__global__ void copy_cur(const int* __restrict__ offo, int* __restrict__ cur, int n) {
    int idx = blockIdx.x * blockDim.x + threadIdx.x;
    if (idx >= T_LEN * n) return;
    int t = idx / n, i = idx - t * n;
    cur[idx] = offo[t * (n + 1) + i];
}

__global__ void scatter_perm(const int* __restrict__ dst, int* __restrict__ cur,
                             int* __restrict__ perm, int n) {
    int idx = blockIdx.x * blockDim.x + threadIdx.x;
    if (idx >= T_LEN * NE) return;
    int t = idx / NE, e = idx - t * NE;
    int d = dst[idx];
    int pos = atomicAdd(&cur[t * n + d], 1);
    perm[t * NE + pos] = e;
}

// src_sorted[t][i] = src[t][perm[t][i]] : removes one level of the gather chain
__global__ void src_sorted_k(const int* __restrict__ src, const int* __restrict__ perm,
                             int* __restrict__ out) {
    int idx = blockIdx.x * blockDim.x + threadIdx.x;
    if (idx >= T_LEN * NE) return;
    int t = idx / NE;
    out[idx] = src[(size_t)t * NE + perm[idx]];
}

// ---------------- fused relation weights (f32) ----------------
__global__ __launch_bounds__(256) void build_fused(
    const float* __restrict__ w, const float* __restrict__ b,
    const float* __restrict__ ra, const float* __restrict__ rm,
    float* __restrict__ Wf, float* __restrict__ bf) {
    int idx = blockIdx.x * 256 + threadIdx.x;
    if (idx >= 128 * 384) return;
    int c = idx / 384, col = idx - c * 384;
    if (col < 128) {
        Wf[c * 384 + col] = w[16384 + c * 128 + col];
        if (c == 0) bf[col] = b[128 + col];
    } else {
        int sec = (col - 128) >> 7;
        int hc = (col - 128) & 127;
        int h = hc >> 5, e2 = hc & 31;
        const float* A = (sec == 0 ? ra : rm) + h * 1024;
        const float* wsrc = w + (sec == 0 ? 0 : 2) * 16384;
        const float* bsrc = b + (sec == 0 ? 0 : 2) * 128;
        float s = 0.f, sb = 0.f;
#pragma unroll
        for (int d = 0; d < 32; ++d) {
            float a = A[d * 32 + e2];
            s += wsrc[c * 128 + h * 32 + d] * a;
            sb += bsrc[h * 32 + d] * a;
        }
        Wf[c * 384 + col] = s;
        if (c == 0) bf[col] = sb;
    }
}

// ---------------- B prep: split f32 W[128][N] into fragment-ready bf16 hi/lo ----------------
__global__ void bprep_kernel(const float* __restrict__ W, unsigned short* __restrict__ prep, int N) {
    int idx = blockIdx.x * blockDim.x + threadIdx.x;
    if (idx >= 128 * N) return;
    int k = idx / N, n = idx - k * N;
    float v = W[idx];
    unsigned short hi = f2bf(v);
    unsigned short lo = f2bf(v - bf2f(hi));
    int nt = n >> 6, nl = n & 63;
    size_t base = (size_t)nt * 16384 + (size_t)nl * 128 + k;
    prep[base] = hi;
    prep[base + 8192] = lo;
}

// ---------------- MFMA GEMM: C = epi( A[M,128] @ W[128,N] + bias ) ----------------
// split-bf16 3-term. BM=128, BN=64, 4 waves (2x2).
// EPI: 0 plain f32; 1 relu f32; 2 skip-blend f32; 3 qkm-split (q f32 stride128, km bf16 stride256)
template <bool GATHER, int EPI>
__global__ __launch_bounds__(256) void gemm_mfma(
    const float* __restrict__ A, const int* __restrict__ ids,
    const unsigned short* __restrict__ prep, const float* __restrict__ bias,
    float* __restrict__ C, const float* __restrict__ Xold,
    const float* __restrict__ skipPtr, unsigned short* __restrict__ km,
    int M, int NC) {
    __shared__ __align__(16) char smem[65536];  // Ah [128][256B] + Al at +32768, XOR-swizzled

    const int tid = threadIdx.x;
    const int lane = tid & 63;
    const int wid = tid >> 6;
    const int wm = wid >> 1, wn = wid & 1;
    const int m0 = blockIdx.x * 128;
    const int n0 = blockIdx.y * 64;
    const int l15 = lane & 15, l4 = lane >> 4;

    const unsigned short* bp = prep + (size_t)blockIdx.y * 16384;
    short8 bh[2][4], bl[2][4];
#pragma unroll
    for (int nf = 0; nf < 2; ++nf) {
        int ncol = wn * 32 + nf * 16 + l15;
#pragma unroll
        for (int ks = 0; ks < 4; ++ks) {
            size_t off = (size_t)ncol * 128 + ks * 32 + l4 * 8;
            bh[nf][ks] = *(const short8*)(bp + off);
            bl[nf][ks] = *(const short8*)(bp + 8192 + off);
        }
    }

#pragma unroll
    for (int i = 0; i < 16; ++i) {
        int flat = i * 256 + tid;
        int r = flat >> 5, c4 = flat & 31;
        int gr = m0 + r;
        if (gr >= M) gr = M - 1;
        int arow = GATHER ? ids[gr] : gr;
        float4 v = *(const float4*)(A + (size_t)arow * 128 + c4 * 4);
        unsigned short h0 = f2bf(v.x), h1 = f2bf(v.y), h2 = f2bf(v.z), h3 = f2bf(v.w);
        unsigned short q0 = f2bf(v.x - bf2f(h0)), q1 = f2bf(v.y - bf2f(h1));
        unsigned short q2 = f2bf(v.z - bf2f(h2)), q3 = f2bf(v.w - bf2f(h3));
        uint2 hp, lp;
        hp.x = (unsigned)h0 | ((unsigned)h1 << 16);
        hp.y = (unsigned)h2 | ((unsigned)h3 << 16);
        lp.x = (unsigned)q0 | ((unsigned)q1 << 16);
        lp.y = (unsigned)q2 | ((unsigned)q3 << 16);
        int off = r * 256 + ((c4 * 8) ^ ((r & 7) << 4));
        *(uint2*)(smem + off) = hp;
        *(uint2*)(smem + 32768 + off) = lp;
    }
    __syncthreads();

    f32x4 acc[4][2];
#pragma unroll
    for (int m = 0; m < 4; ++m)
#pragma unroll
        for (int nf = 0; nf < 2; ++nf) acc[m][nf] = (f32x4)0.f;

#pragma unroll
    for (int ks = 0; ks < 4; ++ks) {
        short8 ah[4], al[4];
#pragma unroll
        for (int m = 0; m < 4; ++m) {
            int row = wm * 64 + m * 16 + l15;
            int off = row * 256 + ((ks * 64 + l4 * 16) ^ ((row & 7) << 4));
            ah[m] = *(const short8*)(smem + off);
            al[m] = *(const short8*)(smem + 32768 + off);
        }
#pragma unroll
        for (int m = 0; m < 4; ++m)
#pragma unroll
            for (int nf = 0; nf < 2; ++nf) {
                acc[m][nf] = __builtin_amdgcn_mfma_f32_16x16x32_bf16(al[m], bh[nf][ks], acc[m][nf], 0, 0, 0);
                acc[m][nf] = __builtin_amdgcn_mfma_f32_16x16x32_bf16(ah[m], bl[nf][ks], acc[m][nf], 0, 0, 0);
                acc[m][nf] = __builtin_amdgcn_mfma_f32_16x16x32_bf16(ah[m], bh[nf][ks], acc[m][nf], 0, 0, 0);
            }
    }

    float g = 0.f;
    if (EPI == 2) g = 1.f / (1.f + expf(-skipPtr[0]));
    float bias_v[2];
#pragma unroll
    for (int nf = 0; nf < 2; ++nf) bias_v[nf] = bias[n0 + wn * 32 + nf * 16 + l15];

#pragma unroll
    for (int m = 0; m < 4; ++m) {
#pragma unroll
        for (int nf = 0; nf < 2; ++nf) {
            int gc = n0 + wn * 32 + nf * 16 + l15;
#pragma unroll
            for (int i = 0; i < 4; ++i) {
                int gr = m0 + wm * 64 + m * 16 + l4 * 4 + i;
                if (gr >= M) continue;
                float x = acc[m][nf][i] + bias_v[nf];
                if (EPI == 1) x = fmaxf(x, 0.f);
                if (EPI == 2) {
                    float xo = Xold[(size_t)gr * NC + gc];
                    x = g * x + (1.f - g) * xo;
                }
                if (EPI == 3) {
                    if (gc < 128) C[(size_t)gr * 128 + gc] = x;
                    else km[(size_t)gr * 256 + (gc - 128)] = f2bf(x);
                } else {
                    C[(size_t)gr * NC + gc] = x;
                }
            }
        }
    }
}

// ---------------- edge aggregation: bf16 k/m gather, online softmax, fused gelu ----------------
// 4 slots per (t_local, dst_node, head); lane bits[1:0]=head, [3:2]=slot.
__global__ __launch_bounds__(256) void agg_edges(
    const float* __restrict__ qD,            // [TCHUNK*nDst, 128] f32
    const unsigned short* __restrict__ kmS,  // [TCHUNK*nSrc, 256] bf16: k at 0, m at 128
    const int* __restrict__ off,             // [T_LEN, nDst+1]
    const int* __restrict__ ssrc,            // [T_LEN, NE] dst-sorted src ids
    const float* __restrict__ relp,          // [H]
    float* __restrict__ agg,                 // [TCHUNK*nDst, 128] (gelu applied)
    int nDst, int nSrc, int tBase) {
    int idx = blockIdx.x * 256 + threadIdx.x;
    int total = TCHUNK * nDst * NH * 4;
    if (idx >= total) return;
    int h = idx & 3;
    int slot = (idx >> 2) & 3;
    int node = (idx >> 4) % nDst;
    int tl = (idx >> 4) / nDst;
    int t = tBase + tl;

    size_t drow = (size_t)(tl * nDst + node);
    float p = relp[h] * 0.17677669529663687f;

    const float4* qp = (const float4*)(qD + drow * 128 + h * HD);
    float qr[HD];
#pragma unroll
    for (int j = 0; j < 8; j++) {
        float4 v = qp[j];
        qr[4 * j + 0] = v.x * p; qr[4 * j + 1] = v.y * p;
        qr[4 * j + 2] = v.z * p; qr[4 * j + 3] = v.w * p;
    }

    float m = -INFINITY, z = 0.f;
    float acc[HD];
#pragma unroll
    for (int d = 0; d < HD; d++) acc[d] = 0.f;

    int e0 = off[t * (nDst + 1) + node], e1 = off[t * (nDst + 1) + node + 1];
    const int* ssT = ssrc + (size_t)t * NE;

    for (int i = e0 + slot; i < e1; i += 4) {
        int s = ssT[i];
        const uint4* kp = (const uint4*)(kmS + ((size_t)(tl * nSrc + s)) * 256);
        uint ku[16], mu_[16];
        *(uint4*)(ku + 0) = kp[h * 4 + 0];
        *(uint4*)(ku + 4) = kp[h * 4 + 1];
        *(uint4*)(ku + 8) = kp[h * 4 + 2];
        *(uint4*)(ku + 12) = kp[h * 4 + 3];
        *(uint4*)(mu_ + 0) = kp[16 + h * 4 + 0];
        *(uint4*)(mu_ + 4) = kp[16 + h * 4 + 1];
        *(uint4*)(mu_ + 8) = kp[16 + h * 4 + 2];
        *(uint4*)(mu_ + 12) = kp[16 + h * 4 + 3];

        float dot = 0.f;
#pragma unroll
        for (int j = 0; j < 16; ++j) {
            float2 f = bf2x(ku[j]);
            dot = fmaf(qr[2 * j], f.x, dot);
            dot = fmaf(qr[2 * j + 1], f.y, dot);
        }
        float mn = fmaxf(m, dot);
        float c = __expf(m - mn);
        float w = __expf(dot - mn);
        z = z * c + w;
#pragma unroll
        for (int j = 0; j < 16; ++j) {
            float2 f = bf2x(mu_[j]);
            acc[2 * j] = fmaf(w, f.x, acc[2 * j] * c);
            acc[2 * j + 1] = fmaf(w, f.y, acc[2 * j + 1] * c);
        }
        m = mn;
    }

#pragma unroll
    for (int lm = 4; lm <= 8; lm <<= 1) {
        float mo = __shfl_xor(m, lm);
        float zo = __shfl_xor(z, lm);
        float mn = fmaxf(m, mo);
        float s1 = (m > -INFINITY) ? __expf(m - mn) : 0.f;
        float s2 = (mo > -INFINITY) ? __expf(mo - mn) : 0.f;
        z = z * s1 + zo * s2;
#pragma unroll
        for (int d = 0; d < HD; d++) {
            float ao = __shfl_xor(acc[d], lm);
            acc[d] = acc[d] * s1 + ao * s2;
        }
        m = mn;
    }

    if (slot == 0) {
        float inv = 1.f / (z + 1e-16f);
        float* op = agg + drow * CH + h * HD;
#pragma unroll
        for (int d = 0; d < HD; d++) {
            float v = acc[d] * inv;
            v = 0.5f * v * (1.f + erff(v * 0.70710678118654752f));  // fused exact gelu
            op[d] = v;
        }
    }
}

__global__ void gather_traj(const float* __restrict__ tkg, const int* __restrict__ traj,
                            const int* __restrict__ tki, float* __restrict__ outp) {
    int idx = blockIdx.x * blockDim.x + threadIdx.x;
    if (idx >= 64 * 128 * 128) return;
    int r = idx >> 7, c2 = idx & 127;
    int t = tki[r], n = traj[r];
    outp[idx] = tkg[((size_t)t * NLL + n) * CH + c2];
}

// ---------------- launch ----------------
extern "C" void kernel_launch(void* const* d_in, const int* in_sizes, int n_in,
                              void* d_out, int out_size, void* d_ws, size_t ws_size,
                              hipStream_t stream) {
    (void)in_sizes; (void)n_in; (void)out_size; (void)ws_size;
    const float* user_emb = (const float*)d_in[0];
    const float* loc_emb = (const float*)d_in[1];
    const float* lin_user_w = (const float*)d_in[2];
    const float* lin_user_b = (const float*)d_in[3];
    const float* lin_loc_w = (const float*)d_in[4];
    const float* lin_loc_b = (const float*)d_in[5];
    const float* w_user = (const float*)d_in[6];
    const float* b_user = (const float*)d_in[7];
    const float* w_loc = (const float*)d_in[8];
    const float* b_loc = (const float*)d_in[9];
    const float* rel_a = (const float*)d_in[10];
    const float* rel_m = (const float*)d_in[11];
    const float* rel_p = (const float*)d_in[12];
    const float* skip = (const float*)d_in[13];
    const float* lin2_w = (const float*)d_in[14];
    const float* lin2_b = (const float*)d_in[15];
    const int* user_ids = (const int*)d_in[16];
    const int* loc_ids = (const int*)d_in[17];
    const int* ei_ul_src = (const int*)d_in[18];
    const int* ei_ul_dst = (const int*)d_in[19];
    const int* ei_lu_src = (const int*)d_in[20];
    const int* ei_lu_dst = (const int*)d_in[21];
    const int* traj = (const int*)d_in[22];
    const int* tkg_idx = (const int*)d_in[23];
    float* outp = (float*)d_out;

    size_t woff = 0;
    char* base = (char*)d_ws;
    auto carve = [&](size_t bytes) -> void* {
        void* p = base + woff;
        woff += (bytes + 255) & ~(size_t)255;
        return p;
    };
    float* xu = (float*)carve((size_t)T_LEN * NUU * 128 * 4);
    float* xl = (float*)carve((size_t)T_LEN * NLL * 128 * 4);
    float* q_u = (float*)carve((size_t)TCHUNK * NUU * 128 * 4);
    float* q_l = (float*)carve((size_t)TCHUNK * NLL * 128 * 4);
    unsigned short* km_u = (unsigned short*)carve((size_t)TCHUNK * NUU * 256 * 2);
    unsigned short* km_l = (unsigned short*)carve((size_t)TCHUNK * NLL * 256 * 2);
    float* agg_u = (float*)carve((size_t)TCHUNK * NUU * 128 * 4);
    float* agg_l = (float*)carve((size_t)TCHUNK * NLL * 128 * 4);
    float* wf_u = (float*)carve(128 * 384 * 4);
    float* bf_u = (float*)carve(384 * 4);
    float* wf_l = (float*)carve(128 * 384 * 4);
    float* bf_l = (float*)carve(384 * 4);
    int* deg_ul = (int*)carve((size_t)T_LEN * NLL * 4);
    int* cur_ul = (int*)carve((size_t)T_LEN * NLL * 4);
    int* off_ul = (int*)carve((size_t)T_LEN * (NLL + 1) * 4);
    int* perm_ul = (int*)carve((size_t)T_LEN * NE * 4);
    int* ss_ul = (int*)carve((size_t)T_LEN * NE * 4);
    int* deg_lu = (int*)carve((size_t)T_LEN * NUU * 4);
    int* cur_lu = (int*)carve((size_t)T_LEN * NUU * 4);
    int* off_lu = (int*)carve((size_t)T_LEN * (NUU + 1) * 4);
    int* perm_lu = (int*)carve((size_t)T_LEN * NE * 4);
    int* ss_lu = (int*)carve((size_t)T_LEN * NE * 4);
    unsigned short* bp_lin_u = (unsigned short*)carve(128 * 512);
    unsigned short* bp_lin_l = (unsigned short*)carve(128 * 512);
    unsigned short* bp_lin2 = (unsigned short*)carve(128 * 512);
    unsigned short* bp_upd_u[2] = {(unsigned short*)carve(128 * 512), (unsigned short*)carve(128 * 512)};
    unsigned short* bp_upd_l[2] = {(unsigned short*)carve(128 * 512), (unsigned short*)carve(128 * 512)};
    unsigned short* bp_wf_u = (unsigned short*)carve(384 * 512);
    unsigned short* bp_wf_l = (unsigned short*)carve(384 * 512);

    // ---- CSR build ----
    fill_zero_int<<<cdiv(T_LEN * NLL, 256), 256, 0, stream>>>(deg_ul, T_LEN * NLL);
    fill_zero_int<<<cdiv(T_LEN * NUU, 256), 256, 0, stream>>>(deg_lu, T_LEN * NUU);
    histo_kernel<<<cdiv(T_LEN * NE, 256), 256, 0, stream>>>(ei_ul_dst, deg_ul, NLL);
    histo_kernel<<<cdiv(T_LEN * NE, 256), 256, 0, stream>>>(ei_lu_dst, deg_lu, NUU);
    scan_off<<<T_LEN, 256, 0, stream>>>(deg_ul, off_ul, NLL);
    scan_off<<<T_LEN, 256, 0, stream>>>(deg_lu, off_lu, NUU);
    copy_cur<<<cdiv(T_LEN * NLL, 256), 256, 0, stream>>>(off_ul, cur_ul, NLL);
    copy_cur<<<cdiv(T_LEN * NUU, 256), 256, 0, stream>>>(off_lu, cur_lu, NUU);
    scatter_perm<<<cdiv(T_LEN * NE, 256), 256, 0, stream>>>(ei_ul_dst, cur_ul, perm_ul, NLL);
    scatter_perm<<<cdiv(T_LEN * NE, 256), 256, 0, stream>>>(ei_lu_dst, cur_lu, perm_lu, NUU);
    src_sorted_k<<<cdiv(T_LEN * NE, 256), 256, 0, stream>>>(ei_ul_src, perm_ul, ss_ul);
    src_sorted_k<<<cdiv(T_LEN * NE, 256), 256, 0, stream>>>(ei_lu_src, perm_lu, ss_lu);

    // ---- weight preps ----
    bprep_kernel<<<64, 256, 0, stream>>>(lin_user_w, bp_lin_u, 128);
    bprep_kernel<<<64, 256, 0, stream>>>(lin_loc_w, bp_lin_l, 128);
    bprep_kernel<<<64, 256, 0, stream>>>(lin2_w, bp_lin2, 128);
    for (int l = 0; l < 2; ++l) {
        bprep_kernel<<<64, 256, 0, stream>>>(w_user + (size_t)(l * 4 + 3) * 16384, bp_upd_u[l], 128);
        bprep_kernel<<<64, 256, 0, stream>>>(w_loc + (size_t)(l * 4 + 3) * 16384, bp_upd_l[l], 128);
    }

    // ---- embed + linear + relu ----
    gemm_mfma<true, 1><<<dim3(cdiv(T_LEN * NUU, 128), 2), 256, 0, stream>>>(
        user_emb, user_ids, bp_lin_u, lin_user_b, xu, nullptr, nullptr, nullptr, T_LEN * NUU, 128);
    gemm_mfma<true, 1><<<dim3(cdiv(T_LEN * NLL, 128), 2), 256, 0, stream>>>(
        loc_emb, loc_ids, bp_lin_l, lin_loc_b, xl, nullptr, nullptr, nullptr, T_LEN * NLL, 128);

    // ---- HGT layers ----
    for (int l = 0; l < 2; ++l) {
        build_fused<<<cdiv(128 * 384, 256), 256, 0, stream>>>(
            w_user + (size_t)l * 4 * 16384, b_user + l * 512,
            rel_a + (size_t)(l * 2 + 0) * 4096, rel_m + (size_t)(l * 2 + 0) * 4096, wf_u, bf_u);
        build_fused<<<cdiv(128 * 384, 256), 256, 0, stream>>>(
            w_loc + (size_t)l * 4 * 16384, b_loc + l * 512,
            rel_a + (size_t)(l * 2 + 1) * 4096, rel_m + (size_t)(l * 2 + 1) * 4096, wf_l, bf_l);
        bprep_kernel<<<192, 256, 0, stream>>>(wf_u, bp_wf_u, 384);
        bprep_kernel<<<192, 256, 0, stream>>>(wf_l, bp_wf_l, 384);

        for (int tb = 0; tb < T_LEN; tb += TCHUNK) {
            const int MU = TCHUNK * NUU;   // 16000
            const int ML = TCHUNK * NLL;   // 40000
            float* xu_c = xu + (size_t)tb * NUU * 128;
            float* xl_c = xl + (size_t)tb * NLL * 128;

            gemm_mfma<false, 3><<<dim3(cdiv(MU, 128), 6), 256, 0, stream>>>(
                xu_c, nullptr, bp_wf_u, bf_u, q_u, nullptr, nullptr, km_u, MU, 384);
            gemm_mfma<false, 3><<<dim3(cdiv(ML, 128), 6), 256, 0, stream>>>(
                xl_c, nullptr, bp_wf_l, bf_l, q_l, nullptr, nullptr, km_l, ML, 384);

            agg_edges<<<cdiv(TCHUNK * NLL * NH * 4, 256), 256, 0, stream>>>(
                q_l, km_u, off_ul, ss_ul, rel_p + (l * 2 + 0) * 4, agg_l, NLL, NUU, tb);
            agg_edges<<<cdiv(TCHUNK * NUU * NH * 4, 256), 256, 0, stream>>>(
                q_u, km_l, off_lu, ss_lu, rel_p + (l * 2 + 1) * 4, agg_u, NUU, NLL, tb);

            gemm_mfma<false, 2><<<dim3(cdiv(MU, 128), 2), 256, 0, stream>>>(
                agg_u, nullptr, bp_upd_u[l], b_user + l * 512 + 384,
                xu_c, xu_c, skip + l * 2 + 0, nullptr, MU, 128);
            gemm_mfma<false, 2><<<dim3(cdiv(ML, 128), 2), 256, 0, stream>>>(
                agg_l, nullptr, bp_upd_l[l], b_loc + l * 512 + 384,
                xl_c, xl_c, skip + l * 2 + 1, nullptr, ML, 128);
        }
    }

    // ---- lin2 -> tkg_out region of d_out ----
    float* tkg_out = outp + (size_t)64 * 128 * 128;
    gemm_mfma<false, 0><<<dim3(cdiv(T_LEN * NLL, 128), 2), 256, 0, stream>>>(
        xl, nullptr, bp_lin2, lin2_b, tkg_out, nullptr, nullptr, nullptr, T_LEN * NLL, 128);

    // ---- trajectory gather ----
    gather_traj<<<cdiv(64 * 128 * 128, 256), 256, 0, stream>>>(tkg_out, traj, tkg_idx, outp);
}